// Round 13
// baseline (25785.129 us; speedup 1.0000x reference)
//
#include <hip/hip_runtime.h>
#include <math.h>

#define NN 4096
#define TSTEPS 50

// 12-bit fixed-point weight quantization: w = QSTEP * q, q in [-2048, 2047]
#define QSTEP 4.8828125e-5f   // 0.1 / 2048
#define QINV  20480.0f

// ws float offsets (state/vector arrays at front of ws)
enum {
  RS0 = 0*NN, RS1 = 1*NN, RS2 = 2*NN, RI0 = 3*NN, RI1 = 4*NN,
  VI0 = 5*NN, VA0A = 6*NN, VA0B = 7*NN, VB1 = 8*NN, VI1 = 9*NN,
  VA1A = 10*NN, VA1B = 11*NN, VB2 = 12*NN, VB0 = 13*NN, RD = 14*NN,
  SS0 = 15*NN, SS1 = 16*NN, SS2 = 17*NN, II0 = 18*NN, II1 = 19*NN,
  MEANS = 20*NN   // [0],[1] = means; [32] = arrival counter (int)
};
#define CNT_IDX (MEANS + 32)
#define WS_F32_FLOATS (21*NN)
#define WS_F32_BYTES  ((size_t)WS_F32_FLOATS*4)      // 4096-aligned
#define MAT_ELEMS     ((size_t)NN*NN)
// dense 12-bit: 8 weights -> 3 dwords; per matrix: 4096*1536 uints = 24 MiB
#define ROW_UINTS     1536
#define MAT_UINTS     ((size_t)NN*ROW_UINTS)
#define Q12_OFF       (WS_F32_BYTES)
#define WS_NEEDED_Q12 (Q12_OFF + 8*MAT_UINTS*4)

__device__ __forceinline__ float softplusf(float x){
    return fmaxf(x, 0.0f) + log1pf(expf(-fabsf(x)));
}

__global__ void k_init(const float* __restrict__ data,
                       const float* __restrict__ s0, const float* __restrict__ s1,
                       const float* __restrict__ s2, const float* __restrict__ i0,
                       const float* __restrict__ i1, float* __restrict__ ws){
    int i = blockIdx.x*blockDim.x + threadIdx.x;
    if (i >= NN) return;
    ws[RD+i] = softplusf(data[i]);
    float a=s0[i], b=s1[i], c=s2[i], d=i0[i], e=i1[i];
    ws[SS0+i]=a; ws[SS1+i]=b; ws[SS2+i]=c; ws[II0+i]=d; ws[II1+i]=e;
    ws[RS0+i]=softplusf(a); ws[RS1+i]=softplusf(b); ws[RS2+i]=softplusf(c);
    ws[RI0+i]=softplusf(d); ws[RI1+i]=softplusf(e);
    if (i == 0) *reinterpret_cast<int*>(ws + CNT_IDX) = 0;
}

__device__ __forceinline__ int quant12(float w){
    int q = __float2int_rn(w * QINV);
    q = max(-2048, min(2047, q));
    return q;
}

// 8 matrices x 8192 blocks; 8 weights/thread; LDS bounce for coalesced stores.
// format per 8-weight group:
//  d0 = q0|q1<<12|q6[7:0]<<24 ; d1 = q2|q3<<12|q6[11:8]<<24|q7[3:0]<<28
//  d2 = q4|q5<<12|q7[11:4]<<24
__global__ __launch_bounds__(256) void k_cvt12(const float* __restrict__ w0,
                                               const float* __restrict__ w1,
                                               const float* __restrict__ w2,
                                               const float* __restrict__ w3,
                                               const float* __restrict__ w4,
                                               const float* __restrict__ w5,
                                               const float* __restrict__ w6,
                                               const float* __restrict__ w7,
                                               uint* __restrict__ q12B){
    int j = blockIdx.x >> 13;
    int inner = blockIdx.x & 8191;
    const float* w;
    switch (j){
      case 0: w = w0; break; case 1: w = w1; break;
      case 2: w = w2; break; case 3: w = w3; break;
      case 4: w = w4; break; case 5: w = w5; break;
      case 6: w = w6; break; default: w = w7; break;
    }
    uint* q12 = q12B + (size_t)j * MAT_UINTS + (size_t)inner * 768;
    size_t e = ((size_t)inner*256 + threadIdx.x)*8;
    float4 a = *reinterpret_cast<const float4*>(w + e);
    float4 b = *reinterpret_cast<const float4*>(w + e + 4);
    uint u0=(uint)quant12(a.x)&0xFFF, u1=(uint)quant12(a.y)&0xFFF;
    uint u2=(uint)quant12(a.z)&0xFFF, u3=(uint)quant12(a.w)&0xFFF;
    uint u4=(uint)quant12(b.x)&0xFFF, u5=(uint)quant12(b.y)&0xFFF;
    uint u6=(uint)quant12(b.z)&0xFFF, u7=(uint)quant12(b.w)&0xFFF;
    __shared__ uint lds[768];
    lds[threadIdx.x*3+0] = u0 | (u1<<12) | ((u6&0xFFu)<<24);
    lds[threadIdx.x*3+1] = u2 | (u3<<12) | (((u6>>8)&0xFu)<<24) | ((u7&0xFu)<<28);
    lds[threadIdx.x*3+2] = u4 | (u5<<12) | (((u7>>4)&0xFFu)<<24);
    __syncthreads();
    if (threadIdx.x < 192){
        uint4 v = make_uint4(lds[threadIdx.x*4+0], lds[threadIdx.x*4+1],
                             lds[threadIdx.x*4+2], lds[threadIdx.x*4+3]);
        reinterpret_cast<uint4*>(q12)[threadIdx.x] = v;
    }
}

// ---------- fp32 path (fallback + k_vb0): 2 rows per wave ----------
__device__ __forceinline__ void mv_rows2_f(const float* __restrict__ w,
                                           const float* __restrict__ xg,
                                           float* __restrict__ o,
                                           int rowbase, float* xs){
    for (int k = threadIdx.x; k < NN/4; k += 256)
        reinterpret_cast<float4*>(xs)[k] = reinterpret_cast<const float4*>(xg)[k];
    __syncthreads();
    int wv = threadIdx.x >> 6, lane = threadIdx.x & 63;
    int row = rowbase + wv*2;
    const float* wr0 = w + (size_t)row * NN;
    const float* wr1 = wr0 + NN;
    float acc0 = 0.f, acc1 = 0.f;
#pragma unroll
    for (int h = 0; h < 2; ++h){
        float4 a0[8], a1[8];
#pragma unroll
        for (int k = 0; k < 8; ++k)
            a0[k] = *reinterpret_cast<const float4*>(wr0 + h*2048 + k*256 + lane*4);
#pragma unroll
        for (int k = 0; k < 8; ++k)
            a1[k] = *reinterpret_cast<const float4*>(wr1 + h*2048 + k*256 + lane*4);
#pragma unroll
        for (int k = 0; k < 8; ++k){
            float4 xv = *reinterpret_cast<const float4*>(xs + h*2048 + k*256 + lane*4);
            acc0 = fmaf(a0[k].x, xv.x, acc0); acc1 = fmaf(a1[k].x, xv.x, acc1);
            acc0 = fmaf(a0[k].y, xv.y, acc0); acc1 = fmaf(a1[k].y, xv.y, acc1);
            acc0 = fmaf(a0[k].z, xv.z, acc0); acc1 = fmaf(a1[k].z, xv.z, acc1);
            acc0 = fmaf(a0[k].w, xv.w, acc0); acc1 = fmaf(a1[k].w, xv.w, acc1);
        }
    }
#pragma unroll
    for (int off = 32; off; off >>= 1){
        acc0 += __shfl_down(acc0, off, 64);
        acc1 += __shfl_down(acc1, off, 64);
    }
    if (lane == 0){ o[row] = acc0; o[row+1] = acc1; }
}

__global__ __launch_bounds__(256) void k_vb0(const float* __restrict__ wpf0,
                                             float* __restrict__ ws){
    __shared__ float xs[NN];
    mv_rows2_f(wpf0, ws + RD, ws + VB0, blockIdx.x * 8, xs);
}

// ---------- dense-12-bit quantized path ----------
__device__ __forceinline__ void acc8(uint3 d, float4 xa, float4 xb, float& acc){
    int q0 = ((int)(d.x<<20))>>20;
    int q1 = ((int)(d.x<< 8))>>20;
    int q2 = ((int)(d.y<<20))>>20;
    int q3 = ((int)(d.y<< 8))>>20;
    int q4 = ((int)(d.z<<20))>>20;
    int q5 = ((int)(d.z<< 8))>>20;
    int q6 = ((((int)(d.y<<4))>>28)<<8) | (int)(d.x>>24);
    int q7 = ((((int)d.z)>>24)<<4)      | (int)(d.y>>28);
    acc = fmaf((float)q0, xa.x, acc);
    acc = fmaf((float)q1, xa.y, acc);
    acc = fmaf((float)q2, xa.z, acc);
    acc = fmaf((float)q3, xa.w, acc);
    acc = fmaf((float)q4, xb.x, acc);
    acc = fmaf((float)q5, xb.y, acc);
    acc = fmaf((float)q6, xb.z, acc);
    acc = fmaf((float)q7, xb.w, acc);
}

// 2 rows per wave; weight loads batched for MLP; x read from global (r12-exact)
__device__ __forceinline__ void mv_rows2_q2g(const uint* __restrict__ qM,
                                             const float* __restrict__ x,
                                             float* __restrict__ o,
                                             int rowbase){
    int wv = threadIdx.x >> 6, lane = threadIdx.x & 63;
    int row = rowbase + wv*2;
    const uint* r0 = qM + (size_t)row * ROW_UINTS;
    const uint* r1 = r0 + ROW_UINTS;
    uint3 A[8], B[8];
#pragma unroll
    for (int k = 0; k < 8; ++k)
        A[k] = *reinterpret_cast<const uint3*>(r0 + (k*64 + lane)*3);
#pragma unroll
    for (int k = 0; k < 8; ++k)
        B[k] = *reinterpret_cast<const uint3*>(r1 + (k*64 + lane)*3);
    float acc0 = 0.f, acc1 = 0.f;
#pragma unroll
    for (int k = 0; k < 8; ++k){
        const float* xp = x + k*512 + lane*8;
        float4 xa = *reinterpret_cast<const float4*>(xp);
        float4 xb = *reinterpret_cast<const float4*>(xp + 4);
        acc8(A[k], xa, xb, acc0);
        acc8(B[k], xa, xb, acc1);
    }
#pragma unroll
    for (int off = 32; off; off >>= 1){
        acc0 += __shfl_down(acc0, off, 64);
        acc1 += __shfl_down(acc1, off, 64);
    }
    if (lane == 0){ o[row] = acc0 * QSTEP; o[row+1] = acc1 * QSTEP; }
}

// block 0: means. blocks 1..4096: 8 jobs x 512 blocks x 8 rows.
// last-arriving block: fused element-wise state update (or final output write).
__global__ __launch_bounds__(256) void k_step(float* __restrict__ ws,
                                              const uint* __restrict__ q12B,
                                              float* __restrict__ out,
                                              int last){
    const float DT=0.1f, GA=0.8f, GB=1.0f, GD=1.0f, GLK=0.1f, GSOM=0.8f;
    int tid = threadIdx.x;
    if (blockIdx.x == 0){
        float a = 0.f, c = 0.f;
        for (int i = tid; i < NN; i += 256){ a += ws[RS1+i]; c += ws[RS2+i]; }
#pragma unroll
        for (int off = 32; off; off >>= 1){
            a += __shfl_down(a, off, 64);
            c += __shfl_down(c, off, 64);
        }
        __shared__ float sa[4], sc[4];
        int wv = tid >> 6, lane = tid & 63;
        if (lane == 0){ sa[wv] = a; sc[wv] = c; }
        __syncthreads();
        if (tid == 0){
            ws[MEANS+0] = (sa[0]+sa[1]+sa[2]+sa[3]) * (1.f/NN);
            ws[MEANS+1] = (sc[0]+sc[1]+sc[2]+sc[3]) * (1.f/NN);
        }
    } else {
        int b = blockIdx.x - 1;
        int job = b >> 9;
        int rowbase = (b & 511) * 8;
        const float* x; float* o;
        switch (job){
          case 0: x = ws+RS0; o = ws+VI0;  break;
          case 1: x = ws+RI0; o = ws+VA0A; break;
          case 2: x = ws+RS1; o = ws+VA0B; break;
          case 3: x = ws+RS0; o = ws+VB1;  break;
          case 4: x = ws+RS1; o = ws+VI1;  break;
          case 5: x = ws+RI1; o = ws+VA1A; break;
          case 6: x = ws+RS2; o = ws+VA1B; break;
          default:x = ws+RS1; o = ws+VB2;  break;
        }
        mv_rows2_q2g(q12B + (size_t)job * MAT_UINTS, x, o, rowbase);
    }
    // ---- arrival + fused update on last block ----
    __threadfence();
    __syncthreads();
    __shared__ int sdone;
    int* cnt = reinterpret_cast<int*>(ws + CNT_IDX);
    if (tid == 0) sdone = atomicAdd(cnt, 1);
    __syncthreads();
    if (sdone != (int)gridDim.x - 1) return;
    __threadfence();
    float m0 = ws[MEANS+0], m1 = ws[MEANS+1];
    for (int it = 0; it < 16; ++it){
        int i = tid + it*256;
        float s0=ws[SS0+i], s1=ws[SS1+i], s2=ws[SS2+i], i0=ws[II0+i], i1=ws[II1+i];
        float vb0=ws[VB0+i], vb1=ws[VB1+i], vb2=ws[VB2+i];
        float va0=ws[VA0A+i]+ws[VA0B+i];
        float va1=ws[VA1A+i]+ws[VA1B+i];
        float vi0=ws[VI0+i], vi1=ws[VI1+i];
        float ds0 = -GLK*s0 + GB*(vb0-s0) + GA*(va0-s0);
        float ds1 = -GLK*s1 + GB*(vb1-s1) + GA*(va1-s1);
        float ds2 = -GLK*s2 + GB*(vb2-s2);
        float di0 = -GLK*i0 + GD*(vi0-i0) + GSOM*(m0-i0);
        float di1 = -GLK*i1 + GD*(vi1-i1) + GSOM*(m1-i1);
        float ns0 = s0 + DT*ds0;
        float ns1 = s1 + DT*ds1;
        float ns2 = DT*ds2;          // faithful to reference: assignment, not +=
        float ni0 = i0 + DT*di0;
        float ni1 = i1 + DT*di1;
        if (last){
            out[i]      = ns0;
            out[NN+i]   = ns1;
            out[2*NN+i] = ns2;
            out[3*NN+i] = ni0;
            out[4*NN+i] = ni1;
        } else {
            ws[SS0+i]=ns0; ws[SS1+i]=ns1; ws[SS2+i]=ns2;
            ws[II0+i]=ni0; ws[II1+i]=ni1;
            ws[RS0+i]=softplusf(ns0); ws[RS1+i]=softplusf(ns1); ws[RS2+i]=softplusf(ns2);
            ws[RI0+i]=softplusf(ni0); ws[RI1+i]=softplusf(ni1);
        }
    }
    if (tid == 0) *cnt = 0;   // ready for next launch / graph replay
}

// ---------- fp32 fallback matvec (ws too small; never expected) ----------
__global__ __launch_bounds__(256) void k_mv(const float* __restrict__ wip0,
                                            const float* __restrict__ wpi0,
                                            const float* __restrict__ wpb0,
                                            const float* __restrict__ wpf1,
                                            const float* __restrict__ wip1,
                                            const float* __restrict__ wpi1,
                                            const float* __restrict__ wpb1,
                                            const float* __restrict__ wpf2,
                                            float* __restrict__ ws){
    if (blockIdx.x == 0){
        int tid = threadIdx.x;
        float a = 0.f, c = 0.f;
        for (int i = tid; i < NN; i += 256){ a += ws[RS1+i]; c += ws[RS2+i]; }
#pragma unroll
        for (int off = 32; off; off >>= 1){
            a += __shfl_down(a, off, 64);
            c += __shfl_down(c, off, 64);
        }
        __shared__ float sa[4], sc[4];
        int wv = tid >> 6, lane = tid & 63;
        if (lane == 0){ sa[wv] = a; sc[wv] = c; }
        __syncthreads();
        if (tid == 0){
            ws[MEANS+0] = (sa[0]+sa[1]+sa[2]+sa[3]) * (1.f/NN);
            ws[MEANS+1] = (sc[0]+sc[1]+sc[2]+sc[3]) * (1.f/NN);
        }
        return;
    }
    int b = blockIdx.x - 1;
    int job = b >> 9;
    int rowbase = (b & 511) * 8;
    const float* w; const float* x; float* o;
    switch (job){
      case 0: w = wip0; x = ws+RS0; o = ws+VI0;  break;
      case 1: w = wpi0; x = ws+RI0; o = ws+VA0A; break;
      case 2: w = wpb0; x = ws+RS1; o = ws+VA0B; break;
      case 3: w = wpf1; x = ws+RS0; o = ws+VB1;  break;
      case 4: w = wip1; x = ws+RS1; o = ws+VI1;  break;
      case 5: w = wpi1; x = ws+RI1; o = ws+VA1A; break;
      case 6: w = wpb1; x = ws+RS2; o = ws+VA1B; break;
      default:w = wpf2; x = ws+RS1; o = ws+VB2;  break;
    }
    __shared__ float xs[NN];
    mv_rows2_f(w, x, o, rowbase, xs);
}

__global__ void k_update(float* __restrict__ ws){
    const float DT=0.1f, GA=0.8f, GB=1.0f, GD=1.0f, GLK=0.1f, GSOM=0.8f;
    int i = blockIdx.x*blockDim.x + threadIdx.x;
    if (i >= NN) return;
    float s0=ws[SS0+i], s1=ws[SS1+i], s2=ws[SS2+i], i0=ws[II0+i], i1=ws[II1+i];
    float vb0=ws[VB0+i], vb1=ws[VB1+i], vb2=ws[VB2+i];
    float va0=ws[VA0A+i]+ws[VA0B+i];
    float va1=ws[VA1A+i]+ws[VA1B+i];
    float vi0=ws[VI0+i], vi1=ws[VI1+i];
    float m0=ws[MEANS+0], m1=ws[MEANS+1];
    float ds0 = -GLK*s0 + GB*(vb0-s0) + GA*(va0-s0);
    float ds1 = -GLK*s1 + GB*(vb1-s1) + GA*(va1-s1);
    float ds2 = -GLK*s2 + GB*(vb2-s2);
    float di0 = -GLK*i0 + GD*(vi0-i0) + GSOM*(m0-i0);
    float di1 = -GLK*i1 + GD*(vi1-i1) + GSOM*(m1-i1);
    float ns0 = s0 + DT*ds0;
    float ns1 = s1 + DT*ds1;
    float ns2 = DT*ds2;
    float ni0 = i0 + DT*di0;
    float ni1 = i1 + DT*di1;
    ws[SS0+i]=ns0; ws[SS1+i]=ns1; ws[SS2+i]=ns2; ws[II0+i]=ni0; ws[II1+i]=ni1;
    ws[RS0+i]=softplusf(ns0); ws[RS1+i]=softplusf(ns1); ws[RS2+i]=softplusf(ns2);
    ws[RI0+i]=softplusf(ni0); ws[RI1+i]=softplusf(ni1);
}

__global__ void k_out(const float* __restrict__ ws, float* __restrict__ out){
    int i = blockIdx.x*blockDim.x + threadIdx.x;
    if (i >= 5*NN) return;
    int which = i >> 12;
    int off = i & (NN-1);
    const int src[5] = {SS0, SS1, SS2, II0, II1};
    out[i] = ws[src[which] + off];
}

extern "C" void kernel_launch(void* const* d_in, const int* in_sizes, int n_in,
                              void* d_out, int out_size, void* d_ws, size_t ws_size,
                              hipStream_t stream) {
    const float* data = (const float*)d_in[0];
    const float* s0   = (const float*)d_in[1];
    const float* s1   = (const float*)d_in[2];
    const float* s2   = (const float*)d_in[3];
    const float* i0   = (const float*)d_in[4];
    const float* i1   = (const float*)d_in[5];
    const float* wpf0 = (const float*)d_in[6];
    const float* wpf1 = (const float*)d_in[7];
    const float* wpf2 = (const float*)d_in[8];
    const float* wpb0 = (const float*)d_in[9];
    const float* wpb1 = (const float*)d_in[10];
    const float* wip0 = (const float*)d_in[11];
    const float* wip1 = (const float*)d_in[12];
    const float* wpi0 = (const float*)d_in[13];
    const float* wpi1 = (const float*)d_in[14];
    float* ws  = (float*)d_ws;
    float* out = (float*)d_out;

    k_init<<<(NN+255)/256, 256, 0, stream>>>(data, s0, s1, s2, i0, i1, ws);
    k_vb0<<<NN/8, 256, 0, stream>>>(wpf0, ws);

    if (ws_size >= WS_NEEDED_Q12){
        uint* q12B = (uint*)((char*)d_ws + Q12_OFF);
        k_cvt12<<<8*8192, 256, 0, stream>>>(wip0, wpi0, wpb0, wpf1,
                                            wip1, wpi1, wpb1, wpf2, q12B);
        for (int t = 0; t < TSTEPS; ++t){
            k_step<<<8*NN/8 + 1, 256, 0, stream>>>(ws, q12B, out,
                                                   (t == TSTEPS-1) ? 1 : 0);
        }
    } else {
        for (int t = 0; t < TSTEPS; ++t){
            k_mv<<<8*NN/8 + 1, 256, 0, stream>>>(wip0, wpi0, wpb0, wpf1,
                                                 wip1, wpi1, wpb1, wpf2, ws);
            k_update<<<(NN+255)/256, 256, 0, stream>>>(ws);
        }
        k_out<<<(5*NN+255)/256, 256, 0, stream>>>(ws, out);
    }
}

// Round 14
// 1787.036 us; speedup vs baseline: 14.4290x; 14.4290x over previous
//
#include <hip/hip_runtime.h>
#include <math.h>

#define NN 4096
#define TSTEPS 50

// 12-bit fixed-point weight quantization: w = QSTEP * q, q in [-2048, 2047]
#define QSTEP 4.8828125e-5f   // 0.1 / 2048
#define QINV  20480.0f

// ws float offsets (state/vector arrays at front of ws)
enum {
  RS0 = 0*NN, RS1 = 1*NN, RS2 = 2*NN, RI0 = 3*NN, RI1 = 4*NN,
  VI0 = 5*NN, VA0A = 6*NN, VA0B = 7*NN, VB1 = 8*NN, VI1 = 9*NN,
  VA1A = 10*NN, VA1B = 11*NN, VB2 = 12*NN, VB0 = 13*NN, RD = 14*NN,
  SS0 = 15*NN, SS1 = 16*NN, SS2 = 17*NN, II0 = 18*NN, II1 = 19*NN,
  MEANS = 20*NN
};
#define WS_F32_FLOATS (21*NN)
#define WS_F32_BYTES  ((size_t)WS_F32_FLOATS*4)      // 4096-aligned
#define MAT_ELEMS     ((size_t)NN*NN)
// dense 12-bit: 8 weights -> 3 dwords; per matrix: 4096*1536 uints = 24 MiB
#define ROW_UINTS     1536
#define MAT_UINTS     ((size_t)NN*ROW_UINTS)
#define Q12_OFF       (WS_F32_BYTES)
#define WS_NEEDED_Q12 (Q12_OFF + 8*MAT_UINTS*4)

__device__ __forceinline__ float softplusf(float x){
    return fmaxf(x, 0.0f) + log1pf(expf(-fabsf(x)));
}

__global__ void k_init(const float* __restrict__ data,
                       const float* __restrict__ s0, const float* __restrict__ s1,
                       const float* __restrict__ s2, const float* __restrict__ i0,
                       const float* __restrict__ i1, float* __restrict__ ws){
    int i = blockIdx.x*blockDim.x + threadIdx.x;
    if (i >= NN) return;
    ws[RD+i] = softplusf(data[i]);
    float a=s0[i], b=s1[i], c=s2[i], d=i0[i], e=i1[i];
    ws[SS0+i]=a; ws[SS1+i]=b; ws[SS2+i]=c; ws[II0+i]=d; ws[II1+i]=e;
    ws[RS0+i]=softplusf(a); ws[RS1+i]=softplusf(b); ws[RS2+i]=softplusf(c);
    ws[RI0+i]=softplusf(d); ws[RI1+i]=softplusf(e);
}

__device__ __forceinline__ int quant12(float w){
    int q = __float2int_rn(w * QINV);
    q = max(-2048, min(2047, q));
    return q;
}

// 8 matrices x 8192 blocks; 8 weights/thread; LDS bounce for coalesced stores.
// format per 8-weight group:
//  d0 = q0|q1<<12|q6[7:0]<<24 ; d1 = q2|q3<<12|q6[11:8]<<24|q7[3:0]<<28
//  d2 = q4|q5<<12|q7[11:4]<<24
__global__ __launch_bounds__(256) void k_cvt12(const float* __restrict__ w0,
                                               const float* __restrict__ w1,
                                               const float* __restrict__ w2,
                                               const float* __restrict__ w3,
                                               const float* __restrict__ w4,
                                               const float* __restrict__ w5,
                                               const float* __restrict__ w6,
                                               const float* __restrict__ w7,
                                               uint* __restrict__ q12B){
    int j = blockIdx.x >> 13;
    int inner = blockIdx.x & 8191;
    const float* w;
    switch (j){
      case 0: w = w0; break; case 1: w = w1; break;
      case 2: w = w2; break; case 3: w = w3; break;
      case 4: w = w4; break; case 5: w = w5; break;
      case 6: w = w6; break; default: w = w7; break;
    }
    uint* q12 = q12B + (size_t)j * MAT_UINTS + (size_t)inner * 768;
    size_t e = ((size_t)inner*256 + threadIdx.x)*8;
    float4 a = *reinterpret_cast<const float4*>(w + e);
    float4 b = *reinterpret_cast<const float4*>(w + e + 4);
    uint u0=(uint)quant12(a.x)&0xFFF, u1=(uint)quant12(a.y)&0xFFF;
    uint u2=(uint)quant12(a.z)&0xFFF, u3=(uint)quant12(a.w)&0xFFF;
    uint u4=(uint)quant12(b.x)&0xFFF, u5=(uint)quant12(b.y)&0xFFF;
    uint u6=(uint)quant12(b.z)&0xFFF, u7=(uint)quant12(b.w)&0xFFF;
    __shared__ uint lds[768];
    lds[threadIdx.x*3+0] = u0 | (u1<<12) | ((u6&0xFFu)<<24);
    lds[threadIdx.x*3+1] = u2 | (u3<<12) | (((u6>>8)&0xFu)<<24) | ((u7&0xFu)<<28);
    lds[threadIdx.x*3+2] = u4 | (u5<<12) | (((u7>>4)&0xFFu)<<24);
    __syncthreads();
    if (threadIdx.x < 192){
        uint4 v = make_uint4(lds[threadIdx.x*4+0], lds[threadIdx.x*4+1],
                             lds[threadIdx.x*4+2], lds[threadIdx.x*4+3]);
        reinterpret_cast<uint4*>(q12)[threadIdx.x] = v;
    }
}

// ---------- fp32 path (fallback + k_vb0): 2 rows per wave ----------
__device__ __forceinline__ void mv_rows2_f(const float* __restrict__ w,
                                           const float* __restrict__ xg,
                                           float* __restrict__ o,
                                           int rowbase, float* xs){
    for (int k = threadIdx.x; k < NN/4; k += 256)
        reinterpret_cast<float4*>(xs)[k] = reinterpret_cast<const float4*>(xg)[k];
    __syncthreads();
    int wv = threadIdx.x >> 6, lane = threadIdx.x & 63;
    int row = rowbase + wv*2;
    const float* wr0 = w + (size_t)row * NN;
    const float* wr1 = wr0 + NN;
    float acc0 = 0.f, acc1 = 0.f;
#pragma unroll
    for (int h = 0; h < 2; ++h){
        float4 a0[8], a1[8];
#pragma unroll
        for (int k = 0; k < 8; ++k)
            a0[k] = *reinterpret_cast<const float4*>(wr0 + h*2048 + k*256 + lane*4);
#pragma unroll
        for (int k = 0; k < 8; ++k)
            a1[k] = *reinterpret_cast<const float4*>(wr1 + h*2048 + k*256 + lane*4);
#pragma unroll
        for (int k = 0; k < 8; ++k){
            float4 xv = *reinterpret_cast<const float4*>(xs + h*2048 + k*256 + lane*4);
            acc0 = fmaf(a0[k].x, xv.x, acc0); acc1 = fmaf(a1[k].x, xv.x, acc1);
            acc0 = fmaf(a0[k].y, xv.y, acc0); acc1 = fmaf(a1[k].y, xv.y, acc1);
            acc0 = fmaf(a0[k].z, xv.z, acc0); acc1 = fmaf(a1[k].z, xv.z, acc1);
            acc0 = fmaf(a0[k].w, xv.w, acc0); acc1 = fmaf(a1[k].w, xv.w, acc1);
        }
    }
#pragma unroll
    for (int off = 32; off; off >>= 1){
        acc0 += __shfl_down(acc0, off, 64);
        acc1 += __shfl_down(acc1, off, 64);
    }
    if (lane == 0){ o[row] = acc0; o[row+1] = acc1; }
}

__global__ __launch_bounds__(256) void k_vb0(const float* __restrict__ wpf0,
                                             float* __restrict__ ws){
    __shared__ float xs[NN];
    mv_rows2_f(wpf0, ws + RD, ws + VB0, blockIdx.x * 8, xs);
}

// ---------- dense-12-bit quantized path ----------
// decode identical to r7; x float4s sourced directly from global (L1/L2)
__device__ __forceinline__ void acc8(uint3 d, float4 xa, float4 xb, float& acc){
    int q0 = ((int)(d.x<<20))>>20;
    int q1 = ((int)(d.x<< 8))>>20;
    int q2 = ((int)(d.y<<20))>>20;
    int q3 = ((int)(d.y<< 8))>>20;
    int q4 = ((int)(d.z<<20))>>20;
    int q5 = ((int)(d.z<< 8))>>20;
    int q6 = ((((int)(d.y<<4))>>28)<<8) | (int)(d.x>>24);
    int q7 = ((((int)d.z)>>24)<<4)      | (int)(d.y>>28);
    acc = fmaf((float)q0, xa.x, acc);
    acc = fmaf((float)q1, xa.y, acc);
    acc = fmaf((float)q2, xa.z, acc);
    acc = fmaf((float)q3, xa.w, acc);
    acc = fmaf((float)q4, xb.x, acc);
    acc = fmaf((float)q5, xb.y, acc);
    acc = fmaf((float)q6, xb.z, acc);
    acc = fmaf((float)q7, xb.w, acc);
}

// 2 rows per wave; weight loads batched for MLP; x read from global
__device__ __forceinline__ void mv_rows2_q2g(const uint* __restrict__ qM,
                                             const float* __restrict__ x,
                                             float* __restrict__ o,
                                             int rowbase){
    int wv = threadIdx.x >> 6, lane = threadIdx.x & 63;
    int row = rowbase + wv*2;
    const uint* r0 = qM + (size_t)row * ROW_UINTS;
    const uint* r1 = r0 + ROW_UINTS;
    uint3 A[8], B[8];
#pragma unroll
    for (int k = 0; k < 8; ++k)
        A[k] = *reinterpret_cast<const uint3*>(r0 + (k*64 + lane)*3);
#pragma unroll
    for (int k = 0; k < 8; ++k)
        B[k] = *reinterpret_cast<const uint3*>(r1 + (k*64 + lane)*3);
    float acc0 = 0.f, acc1 = 0.f;
#pragma unroll
    for (int k = 0; k < 8; ++k){
        const float* xp = x + k*512 + lane*8;
        float4 xa = *reinterpret_cast<const float4*>(xp);
        float4 xb = *reinterpret_cast<const float4*>(xp + 4);
        acc8(A[k], xa, xb, acc0);
        acc8(B[k], xa, xb, acc1);
    }
#pragma unroll
    for (int off = 32; off; off >>= 1){
        acc0 += __shfl_down(acc0, off, 64);
        acc1 += __shfl_down(acc1, off, 64);
    }
    if (lane == 0){ o[row] = acc0 * QSTEP; o[row+1] = acc1 * QSTEP; }
}

// block 0: means. blocks 1..4096: 8 jobs x 512 blocks x 8 rows.
__global__ __launch_bounds__(256) void k_mv_q2(float* __restrict__ ws,
                                               const uint* __restrict__ q12B){
    if (blockIdx.x == 0){
        int tid = threadIdx.x;
        float a = 0.f, c = 0.f;
        for (int i = tid; i < NN; i += 256){ a += ws[RS1+i]; c += ws[RS2+i]; }
#pragma unroll
        for (int off = 32; off; off >>= 1){
            a += __shfl_down(a, off, 64);
            c += __shfl_down(c, off, 64);
        }
        __shared__ float sa[4], sc[4];
        int wv = tid >> 6, lane = tid & 63;
        if (lane == 0){ sa[wv] = a; sc[wv] = c; }
        __syncthreads();
        if (tid == 0){
            ws[MEANS+0] = (sa[0]+sa[1]+sa[2]+sa[3]) * (1.f/NN);
            ws[MEANS+1] = (sc[0]+sc[1]+sc[2]+sc[3]) * (1.f/NN);
        }
        return;
    }
    int b = blockIdx.x - 1;
    int job = b >> 9;
    int rowbase = (b & 511) * 8;
    const float* x; float* o;
    switch (job){
      case 0: x = ws+RS0; o = ws+VI0;  break;
      case 1: x = ws+RI0; o = ws+VA0A; break;
      case 2: x = ws+RS1; o = ws+VA0B; break;
      case 3: x = ws+RS0; o = ws+VB1;  break;
      case 4: x = ws+RS1; o = ws+VI1;  break;
      case 5: x = ws+RI1; o = ws+VA1A; break;
      case 6: x = ws+RS2; o = ws+VA1B; break;
      default:x = ws+RS1; o = ws+VB2;  break;
    }
    mv_rows2_q2g(q12B + (size_t)job * MAT_UINTS, x, o, rowbase);
}

// ---------- fp32 fallback matvec (ws too small; never expected) ----------
__global__ __launch_bounds__(256) void k_mv(const float* __restrict__ wip0,
                                            const float* __restrict__ wpi0,
                                            const float* __restrict__ wpb0,
                                            const float* __restrict__ wpf1,
                                            const float* __restrict__ wip1,
                                            const float* __restrict__ wpi1,
                                            const float* __restrict__ wpb1,
                                            const float* __restrict__ wpf2,
                                            float* __restrict__ ws){
    if (blockIdx.x == 0){
        int tid = threadIdx.x;
        float a = 0.f, c = 0.f;
        for (int i = tid; i < NN; i += 256){ a += ws[RS1+i]; c += ws[RS2+i]; }
#pragma unroll
        for (int off = 32; off; off >>= 1){
            a += __shfl_down(a, off, 64);
            c += __shfl_down(c, off, 64);
        }
        __shared__ float sa[4], sc[4];
        int wv = tid >> 6, lane = tid & 63;
        if (lane == 0){ sa[wv] = a; sc[wv] = c; }
        __syncthreads();
        if (tid == 0){
            ws[MEANS+0] = (sa[0]+sa[1]+sa[2]+sa[3]) * (1.f/NN);
            ws[MEANS+1] = (sc[0]+sc[1]+sc[2]+sc[3]) * (1.f/NN);
        }
        return;
    }
    int b = blockIdx.x - 1;
    int job = b >> 9;
    int rowbase = (b & 511) * 8;
    const float* w; const float* x; float* o;
    switch (job){
      case 0: w = wip0; x = ws+RS0; o = ws+VI0;  break;
      case 1: w = wpi0; x = ws+RI0; o = ws+VA0A; break;
      case 2: w = wpb0; x = ws+RS1; o = ws+VA0B; break;
      case 3: w = wpf1; x = ws+RS0; o = ws+VB1;  break;
      case 4: w = wip1; x = ws+RS1; o = ws+VI1;  break;
      case 5: w = wpi1; x = ws+RI1; o = ws+VA1A; break;
      case 6: w = wpb1; x = ws+RS2; o = ws+VA1B; break;
      default:w = wpf2; x = ws+RS1; o = ws+VB2;  break;
    }
    __shared__ float xs[NN];
    mv_rows2_f(w, x, o, rowbase, xs);
}

// 16 blocks x 256
__global__ void k_update(float* __restrict__ ws){
    const float DT=0.1f, GA=0.8f, GB=1.0f, GD=1.0f, GLK=0.1f, GSOM=0.8f;
    int i = blockIdx.x*blockDim.x + threadIdx.x;
    if (i >= NN) return;
    float s0=ws[SS0+i], s1=ws[SS1+i], s2=ws[SS2+i], i0=ws[II0+i], i1=ws[II1+i];
    float vb0=ws[VB0+i], vb1=ws[VB1+i], vb2=ws[VB2+i];
    float va0=ws[VA0A+i]+ws[VA0B+i];
    float va1=ws[VA1A+i]+ws[VA1B+i];
    float vi0=ws[VI0+i], vi1=ws[VI1+i];
    float m0=ws[MEANS+0], m1=ws[MEANS+1];
    float ds0 = -GLK*s0 + GB*(vb0-s0) + GA*(va0-s0);
    float ds1 = -GLK*s1 + GB*(vb1-s1) + GA*(va1-s1);
    float ds2 = -GLK*s2 + GB*(vb2-s2);
    float di0 = -GLK*i0 + GD*(vi0-i0) + GSOM*(m0-i0);
    float di1 = -GLK*i1 + GD*(vi1-i1) + GSOM*(m1-i1);
    float ns0 = s0 + DT*ds0;
    float ns1 = s1 + DT*ds1;
    float ns2 = DT*ds2;          // faithful to reference: assignment, not +=
    float ni0 = i0 + DT*di0;
    float ni1 = i1 + DT*di1;
    ws[SS0+i]=ns0; ws[SS1+i]=ns1; ws[SS2+i]=ns2; ws[II0+i]=ni0; ws[II1+i]=ni1;
    ws[RS0+i]=softplusf(ns0); ws[RS1+i]=softplusf(ns1); ws[RS2+i]=softplusf(ns2);
    ws[RI0+i]=softplusf(ni0); ws[RI1+i]=softplusf(ni1);
}

__global__ void k_out(const float* __restrict__ ws, float* __restrict__ out){
    int i = blockIdx.x*blockDim.x + threadIdx.x;
    if (i >= 5*NN) return;
    int which = i >> 12;
    int off = i & (NN-1);
    const int src[5] = {SS0, SS1, SS2, II0, II1};
    out[i] = ws[src[which] + off];
}

extern "C" void kernel_launch(void* const* d_in, const int* in_sizes, int n_in,
                              void* d_out, int out_size, void* d_ws, size_t ws_size,
                              hipStream_t stream) {
    const float* data = (const float*)d_in[0];
    const float* s0   = (const float*)d_in[1];
    const float* s1   = (const float*)d_in[2];
    const float* s2   = (const float*)d_in[3];
    const float* i0   = (const float*)d_in[4];
    const float* i1   = (const float*)d_in[5];
    const float* wpf0 = (const float*)d_in[6];
    const float* wpf1 = (const float*)d_in[7];
    const float* wpf2 = (const float*)d_in[8];
    const float* wpb0 = (const float*)d_in[9];
    const float* wpb1 = (const float*)d_in[10];
    const float* wip0 = (const float*)d_in[11];
    const float* wip1 = (const float*)d_in[12];
    const float* wpi0 = (const float*)d_in[13];
    const float* wpi1 = (const float*)d_in[14];
    float* ws  = (float*)d_ws;
    float* out = (float*)d_out;

    k_init<<<(NN+255)/256, 256, 0, stream>>>(data, s0, s1, s2, i0, i1, ws);
    k_vb0<<<NN/8, 256, 0, stream>>>(wpf0, ws);

    if (ws_size >= WS_NEEDED_Q12){
        uint* q12B = (uint*)((char*)d_ws + Q12_OFF);
        k_cvt12<<<8*8192, 256, 0, stream>>>(wip0, wpi0, wpb0, wpf1,
                                            wip1, wpi1, wpb1, wpf2, q12B);
        for (int t = 0; t < TSTEPS; ++t){
            k_mv_q2<<<8*NN/8 + 1, 256, 0, stream>>>(ws, q12B);
            k_update<<<(NN+255)/256, 256, 0, stream>>>(ws);
        }
    } else {
        for (int t = 0; t < TSTEPS; ++t){
            k_mv<<<8*NN/8 + 1, 256, 0, stream>>>(wip0, wpi0, wpb0, wpf1,
                                                 wip1, wpi1, wpb1, wpf2, ws);
            k_update<<<(NN+255)/256, 256, 0, stream>>>(ws);
        }
    }
    k_out<<<(5*NN+255)/256, 256, 0, stream>>>(ws, out);
}